// Round 13
// baseline (187.380 us; speedup 1.0000x reference)
//
#include <hip/hip_runtime.h>

#define T_STEPS 2048
#define NUSERS 4000
#define NLOCAS 4000
#define DD 128
#define KK 64
#define PRED_OUT 4192
#define PRED_IN 8256
#define OUT_EMB 1024000   // 8000*128
#define TAIL_LV 6
#define WB_ROWS 4224      // 4192 padded to 33*128

typedef __attribute__((ext_vector_type(8))) short short8v;
typedef __attribute__((ext_vector_type(8))) unsigned short ushort8v;
typedef __attribute__((ext_vector_type(4))) unsigned short ushort4v;
typedef __attribute__((ext_vector_type(4))) float f32x4;

// ---- ws layout (float offsets) ----
#define WS_NEWU   0          // 262144
#define WS_NEWL   262144
#define WS_KU     524288
#define WS_KL     786432
#define WS_ZB     1048576    // 2048*320 ushort
#define WS_WB     1376256    // 4224*320 ushort
#define WS_ELT    2052096    // 128*2048
#define WS_DRIFT  2314240    // 2048
#define WS_ROWP   2316288    // 4192*16 max
#define WS_INT    2450432    // 14400 ints
#define WS_PVU    2464832    // 2048 int2 = 4096 ints, then KN 2048 ints
#define WS_S      2473024    // ushort S[4192*NT]
// ---- int offsets within WS_INT ----
#define IO_PU     0
#define IO_PL     2048
#define IO_PP     4096
#define IO_LASTU  6144
#define IO_LASTL  8192
#define IO_ORDER  10240
#define IO_OFF    12288      // 2049 entries
#define IO_NLEV   14337

__device__ inline unsigned short f2bf(float f) {
    unsigned int x = __float_as_uint(f);
    unsigned int r = (x + 0x7FFFu + ((x >> 16) & 1u)) >> 16;
    return (unsigned short)r;
}
__device__ inline float bf2f(unsigned short u) {
    return __uint_as_float(((unsigned int)u) << 16);
}

// Fused prep: blocks 0..511 = wave-parallel preds scan (4 t/block);
// blocks 512..1023 = precomp_k (4 t/block) + grid-stride {init copy, convw}.
__global__ __launch_bounds__(256) void prep_kernel(const int* __restrict__ ev,
    const float* __restrict__ emb_in, const float* __restrict__ du,
    const float* __restrict__ dl, const float* __restrict__ kg,
    const float* __restrict__ wihu, const float* __restrict__ bihu,
    const float* __restrict__ bhhu, const float* __restrict__ wihl,
    const float* __restrict__ bihl, const float* __restrict__ bhhl,
    const float* __restrict__ predw,
    float* __restrict__ out, float* __restrict__ KU, float* __restrict__ KL,
    unsigned short* __restrict__ Wb, int* __restrict__ ibase) {
    __shared__ int su[T_STEPS];
    __shared__ int sl[T_STEPS];
    __shared__ float skg[4][KK];
    __shared__ int kn4[4];
    const int tid = threadIdx.x;

    if (blockIdx.x < 512) {
        const int lane = tid & 63;
        const int wid  = tid >> 6;
        for (int i = tid; i < T_STEPS; i += 256) { su[i] = ev[i*5]; sl[i] = ev[i*5+1]; }
        __syncthreads();

        const int t = blockIdx.x * 4 + wid;
        const int u = su[t], l = sl[t], p = ev[t*5 + 2];

        int pu = -1, pl = -1, pp = -1;
        {
            int round = 0;
            while (true) {
                const int q = t - 1 - lane - (round << 6);
                const int squ = (q >= 0) ? su[q] : -1;
                const int sql = (q >= 0) ? sl[q] : -1;
                if (pu < 0) {
                    unsigned long long b = __ballot(squ == u);
                    if (b) pu = t - 1 - (__ffsll(b) - 1) - (round << 6);
                }
                if (pl < 0) {
                    unsigned long long b = __ballot(sql == l);
                    if (b) pl = t - 1 - (__ffsll(b) - 1) - (round << 6);
                }
                if (pp < 0) {
                    unsigned long long b = __ballot(sql == p);
                    if (b) pp = t - 1 - (__ffsll(b) - 1) - (round << 6);
                }
                ++round;
                if ((pu >= 0 && pl >= 0 && pp >= 0) || (t - 1 - (round << 6) < 0)) break;
            }
        }
        int lastu = 1, lastl = 1;
        {
            int round = 0;
            while (true) {
                const int q = t + 1 + lane + (round << 6);
                const int squ = (q < T_STEPS) ? su[q] : -1;
                const int sql = (q < T_STEPS) ? sl[q] : -1;
                if (lastu && __ballot(squ == u)) lastu = 0;
                if (lastl && __ballot(sql == l)) lastl = 0;
                ++round;
                if ((!lastu && !lastl) || (t + 1 + (round << 6) >= T_STEPS)) break;
            }
        }
        if (lane == 0) {
            ibase[IO_PU + t] = pu;
            ibase[IO_PL + t] = pl;
            ibase[IO_PP + t] = pp;
            ibase[IO_LASTU + t] = lastu;
            ibase[IO_LASTL + t] = lastl;
        }
        return;
    }

    // ---- precomp_k for 4 t ----
    const int pb = blockIdx.x - 512;
    if (tid < 4) kn4[tid] = ev[(pb*4 + tid)*5 + 4];
    __syncthreads();
    skg[tid >> 6][tid & 63] = kg[kn4[tid >> 6]*KK + (tid & 63)];
    __syncthreads();
    #pragma unroll
    for (int p = 0; p < 2; ++p) {
        const int sub = p*2 + (tid >> 7);
        const int t = pb*4 + sub;
        const int r = tid & 127;
        const float* wu = wihu + r*193;
        const float* wl = wihl + r*193;
        const float dut = du[t], dlt = dl[t];
        float ku = bihu[r] + bhhu[r] + wu[192]*dut;
        float kl = bihl[r] + bhhl[r] + wl[192]*dlt;
        const float* sk = skg[sub];
        #pragma unroll
        for (int j = 0; j < KK; ++j) {
            float s = sk[j];
            ku += wu[128+j]*s;
            kl += wl[128+j]*s;
        }
        KU[t*DD + r] = ku;
        KL[t*DD + r] = kl;
    }

    // ---- init copy (float4) + convw, grid-stride ----
    const int gsz = 512 * 256;
    const int gid = pb * 256 + tid;
    for (int i = gid; i < OUT_EMB/4; i += gsz)
        ((float4*)out)[i] = ((const float4*)emb_in)[i];
    for (int i = gid; i < WB_ROWS*80; i += gsz) {
        int r = i / 80, kc = (i - r*80) * 4;
        unsigned short o0 = 0, o1 = 0, o2 = 0, o3 = 0;
        if (r < PRED_OUT) {
            const float4 v = *(const float4*)(predw + (size_t)r*PRED_IN + kc);
            o0 = f2bf(v.x); o1 = f2bf(v.y); o2 = f2bf(v.z); o3 = f2bf(v.w);
        }
        unsigned short* dst = Wb + (size_t)r*320 + kc;
        dst[0] = o0; dst[1] = o1; dst[2] = o2; dst[3] = o3;
    }
}

// DAG levels via monotone fixpoint; counting sort into ORDER with OFF[], NLEV.
__global__ __launch_bounds__(1024) void levels_kernel(int* __restrict__ ibase) {
    __shared__ int lev[T_STEPS];
    __shared__ int spu[T_STEPS];
    __shared__ int spl[T_STEPS];
    __shared__ int cnt[T_STEPS + 1];
    __shared__ int changed;
    __shared__ int smax;
    const int tid = threadIdx.x;

    for (int i = tid; i < T_STEPS; i += 1024) {
        spu[i] = ibase[IO_PU + i];
        spl[i] = ibase[IO_PL + i];
        lev[i] = 0;
    }
    if (tid == 0) smax = 0;
    __syncthreads();

    while (true) {
        if (tid == 0) changed = 0;
        __syncthreads();
        for (int i = tid; i < T_STEPS; i += 1024) {
            int nl = 0, a = spu[i], b = spl[i];
            if (a >= 0) nl = lev[a] + 1;
            if (b >= 0) { int v = lev[b] + 1; if (v > nl) nl = v; }
            if (nl > lev[i]) { lev[i] = nl; changed = 1; }
        }
        __syncthreads();
        if (!changed) break;
        __syncthreads();
    }

    for (int i = tid; i <= T_STEPS; i += 1024) cnt[i] = 0;
    __syncthreads();
    for (int i = tid; i < T_STEPS; i += 1024) {
        atomicAdd(&cnt[lev[i]], 1);
        atomicMax(&smax, lev[i]);
    }
    __syncthreads();
    if (tid == 0) {
        int nlev = smax + 1;
        int acc = 0;
        for (int k = 0; k < nlev; ++k) {
            ibase[IO_OFF + k] = acc;
            int c = cnt[k]; cnt[k] = acc; acc += c;
        }
        ibase[IO_OFF + nlev] = acc;
        ibase[IO_NLEV] = nlev;
        for (int k = nlev + 1; k <= TAIL_LV; ++k) ibase[IO_OFF + k] = acc;
    }
    __syncthreads();
    for (int i = tid; i < T_STEPS; i += 1024) {
        int pos = atomicAdd(&cnt[lev[i]], 1);
        ibase[IO_ORDER + pos] = i;
    }
}

// One DAG level per launch (levels 0..TAIL_LV-1). 256 blocks x 512 threads.
__global__ __launch_bounds__(512) void chain_sweep(int lv, const int* __restrict__ ev,
    const float* __restrict__ emb0,
    const float* __restrict__ wihu, const float* __restrict__ whhu,
    const float* __restrict__ whhl, const float* __restrict__ wihl,
    const float* __restrict__ KU, const float* __restrict__ KL,
    float* __restrict__ NEWU, float* __restrict__ NEWL, float* __restrict__ DRIFT,
    const int* __restrict__ ibase) {
    const int start = ibase[IO_OFF + lv];
    const int end   = ibase[IO_OFF + lv + 1];
    if ((int)blockIdx.x >= end - start) return;

    const int tid  = threadIdx.x;
    const int h    = tid >> 8;
    const int r    = tid & 255;
    const int lane = tid & 63;
    const int wid  = tid >> 6;

    float w[128];
    {
        const float* src;
        if (h == 0) src = (r < 128) ? (wihu + r*193) : (whhl + (r-128)*128);
        else        src = (r < 128) ? (whhu + r*128) : (wihl + (r-128)*193);
        #pragma unroll
        for (int j = 0; j < 32; ++j) {
            const float4 v = *(const float4*)(src + j*4);
            w[j*4+0] = v.x; w[j*4+1] = v.y; w[j*4+2] = v.z; w[j*4+3] = v.w;
        }
    }

    __shared__ float xs[256];
    __shared__ float partial[512];
    __shared__ float wsum[8];

    for (int s = start + blockIdx.x; s < end; s += gridDim.x) {
        const int t  = ibase[IO_ORDER + s];
        const int u  = ev[t*5];
        const int l  = ev[t*5 + 1];
        const int pu = ibase[IO_PU + t];
        const int pl = ibase[IO_PL + t];

        float kv = 0.f;
        if (tid < 128) {
            xs[tid] = (pl >= 0) ? NEWL[pl*DD + tid] : emb0[(size_t)(l + NUSERS)*DD + tid];
            kv = KU[t*DD + tid];
        } else if (tid < 256) {
            int d = tid - 128;
            xs[tid] = (pu >= 0) ? NEWU[pu*DD + d] : emb0[(size_t)u*DD + d];
            kv = KL[t*DD + d];
        }
        __syncthreads();                               // B1

        float acc = 0.f;
        {
            const float* xp = xs + h*128;
            #pragma unroll
            for (int j = 0; j < 128; ++j) acc += w[j] * xp[j];
        }
        partial[tid] = acc;
        __syncthreads();                               // B2

        float th = 0.f;
        if (tid < 256) {
            float pre = partial[tid] + partial[256 + tid] + kv;
            th = tanhf(pre);
            float ss = th * th;
            #pragma unroll
            for (int o = 32; o > 0; o >>= 1) ss += __shfl_xor(ss, o, 64);
            if (lane == 0) wsum[wid] = ss;
        }
        __syncthreads();                               // B3

        if (tid < 256) {
            float S  = (tid < 128) ? (wsum[0] + wsum[1]) : (wsum[2] + wsum[3]);
            float sf = 1.f / fmaxf(sqrtf(S), 1e-12f);
            float v2 = th * sf;
            float old = (tid < 128) ? xs[128 + tid] : xs[tid - 128];
            if (tid < 128) NEWU[t*DD + tid]       = v2;
            else           NEWL[t*DD + (tid-128)] = v2;
            float dd = v2 - old;
            float s2 = dd * dd;
            #pragma unroll
            for (int o = 32; o > 0; o >>= 1) s2 += __shfl_xor(s2, o, 64);
            if (lane == 0) wsum[4 + wid] = s2;
        }
        __syncthreads();                               // B4
        if (tid == 0)
            DRIFT[t] = (wsum[4] + wsum[5] + wsum[6] + wsum[7]) * (1.f / 128.f);
    }
}

// Tail: ONE block processes ALL levels >= TAIL_LV sequentially in level order.
__global__ __launch_bounds__(512) void chain_tail(const int* __restrict__ ev,
    const float* __restrict__ emb0,
    const float* __restrict__ wihu, const float* __restrict__ whhu,
    const float* __restrict__ whhl, const float* __restrict__ wihl,
    const float* __restrict__ KU, const float* __restrict__ KL,
    float* __restrict__ NEWU, float* __restrict__ NEWL, float* __restrict__ DRIFT,
    const int* __restrict__ ibase) {
    const int nlev = ibase[IO_NLEV];
    if (nlev <= TAIL_LV) return;
    const int start = ibase[IO_OFF + TAIL_LV];
    const int end   = ibase[IO_OFF + nlev];

    const int tid  = threadIdx.x;
    const int h    = tid >> 8;
    const int r    = tid & 255;
    const int lane = tid & 63;
    const int wid  = tid >> 6;

    float w[128];
    {
        const float* src;
        if (h == 0) src = (r < 128) ? (wihu + r*193) : (whhl + (r-128)*128);
        else        src = (r < 128) ? (whhu + r*128) : (wihl + (r-128)*193);
        #pragma unroll
        for (int j = 0; j < 32; ++j) {
            const float4 v = *(const float4*)(src + j*4);
            w[j*4+0] = v.x; w[j*4+1] = v.y; w[j*4+2] = v.z; w[j*4+3] = v.w;
        }
    }

    __shared__ float xs[256];
    __shared__ float partial[512];
    __shared__ float wsum[8];

    for (int s = start; s < end; ++s) {
        const int t  = ibase[IO_ORDER + s];
        const int u  = ev[t*5];
        const int l  = ev[t*5 + 1];
        const int pu = ibase[IO_PU + t];
        const int pl = ibase[IO_PL + t];

        float kv = 0.f;
        if (tid < 128) {
            xs[tid] = (pl >= 0) ? NEWL[pl*DD + tid] : emb0[(size_t)(l + NUSERS)*DD + tid];
            kv = KU[t*DD + tid];
        } else if (tid < 256) {
            int d = tid - 128;
            xs[tid] = (pu >= 0) ? NEWU[pu*DD + d] : emb0[(size_t)u*DD + d];
            kv = KL[t*DD + d];
        }
        __syncthreads();                               // B1

        float acc = 0.f;
        {
            const float* xp = xs + h*128;
            #pragma unroll
            for (int j = 0; j < 128; ++j) acc += w[j] * xp[j];
        }
        partial[tid] = acc;
        __syncthreads();                               // B2

        float th = 0.f;
        if (tid < 256) {
            float pre = partial[tid] + partial[256 + tid] + kv;
            th = tanhf(pre);
            float ss = th * th;
            #pragma unroll
            for (int o = 32; o > 0; o >>= 1) ss += __shfl_xor(ss, o, 64);
            if (lane == 0) wsum[wid] = ss;
        }
        __syncthreads();                               // B3

        if (tid < 256) {
            float S  = (tid < 128) ? (wsum[0] + wsum[1]) : (wsum[2] + wsum[3]);
            float sf = 1.f / fmaxf(sqrtf(S), 1e-12f);
            float v2 = th * sf;
            float old = (tid < 128) ? xs[128 + tid] : xs[tid - 128];
            if (tid < 128) NEWU[t*DD + tid]       = v2;
            else           NEWL[t*DD + (tid-128)] = v2;
            float dd = v2 - old;
            float s2 = dd * dd;
            #pragma unroll
            for (int o = 32; o > 0; o >>= 1) s2 += __shfl_xor(s2, o, 64);
            if (lane == 0) wsum[4 + wid] = s2;
        }
        __syncthreads();                               // B4
        if (tid == 0)
            DRIFT[t] = (wsum[4] + wsum[5] + wsum[6] + wsum[7]) * (1.f / 128.f);
    }
}

// Wide epilogue: Zb (bf16), ELT, PVU(int2)+KN pack, scatter-last.
__global__ __launch_bounds__(256) void build_z(const int* __restrict__ ev,
    const float* __restrict__ emb0, const float* __restrict__ du,
    const float* __restrict__ pw, const float* __restrict__ projb,
    const float* __restrict__ kg,
    const float* __restrict__ NEWU, const float* __restrict__ NEWL,
    unsigned short* __restrict__ Zb, float* __restrict__ ELT,
    int2* __restrict__ PVU, int* __restrict__ KN,
    float* __restrict__ out, const int* __restrict__ ibase) {
    const int gsz = gridDim.x * blockDim.x;
    const int gid = blockIdx.x * blockDim.x + threadIdx.x;

    for (int i = gid; i < T_STEPS; i += gsz) {
        PVU[i] = make_int2(ev[i*5 + 2], ev[i*5 + 0]);
        KN[i]  = ev[i*5 + 4];
    }

    for (int i = gid; i < T_STEPS*320; i += gsz) {
        int t = i / 320, j = i - t*320;
        float zv;
        if (j < 128) {
            int pu = ibase[IO_PU + t];
            int uu = ev[t*5];
            float eu = (pu >= 0) ? NEWU[pu*DD + j] : emb0[(size_t)uu*DD + j];
            zv = eu * (1.f + pw[j]*du[t] + projb[j]);
        } else if (j < 256) {
            int jj = j - 128;
            int pp = ibase[IO_PP + t];
            int pv = ev[t*5 + 2];
            zv = (pp >= 0) ? NEWL[pp*DD + jj] : emb0[(size_t)(pv + NUSERS)*DD + jj];
        } else {
            int kp = ev[t*5 + 3];
            zv = kg[kp*KK + (j - 256)];
        }
        Zb[i] = f2bf(zv);
    }
    for (int i = gid; i < DD*T_STEPS; i += gsz) {     // ELT[d][t]
        int d = i >> 11, t = i & 2047;
        int pl = ibase[IO_PL + t];
        int l  = ev[t*5 + 1];
        ELT[i] = (pl >= 0) ? NEWL[pl*DD + d] : emb0[(size_t)(l + NUSERS)*DD + d];
    }
    for (int i = gid; i < T_STEPS*DD; i += gsz) {     // scatter last-occurrence
        int t = i >> 7, d = i & 127;
        if (ibase[IO_LASTU + t]) out[(size_t)ev[t*5]*DD + d]            = NEWU[i];
        if (ibase[IO_LASTL + t]) out[(size_t)(ev[t*5+1]+NUSERS)*DD + d] = NEWL[i];
    }
}

// MFMA GEMM: S[r][t] = sum_k W[r][k]*Z[t][k], bf16 output. 128x128 tile, 4 waves.
__global__ __launch_bounds__(256) void pred_dense_mfma(
    const unsigned short* __restrict__ Wb, const unsigned short* __restrict__ Zb,
    unsigned short* __restrict__ S, int NT, int t0) {
    const int tid = threadIdx.x;
    const int l   = tid & 63;
    const int w   = tid >> 6;
    const int wr  = w >> 1, wc = w & 1;
    const int lr  = l & 15;
    const int kg8 = (l >> 4) * 8;
    const int r0  = blockIdx.y * 128 + wr * 64;
    const int tt0 = blockIdx.x * 128 + wc * 64;

    f32x4 acc[4][4];
    #pragma unroll
    for (int m = 0; m < 4; ++m)
        #pragma unroll
        for (int n = 0; n < 4; ++n) acc[m][n] = (f32x4){0.f, 0.f, 0.f, 0.f};

    for (int k0 = 0; k0 < 320; k0 += 32) {
        short8v a[4], b[4];
        #pragma unroll
        for (int m = 0; m < 4; ++m)
            a[m] = *(const short8v*)(Wb + (size_t)(r0 + m*16 + lr)*320 + k0 + kg8);
        #pragma unroll
        for (int n = 0; n < 4; ++n)
            b[n] = *(const short8v*)(Zb + (size_t)(t0 + tt0 + n*16 + lr)*320 + k0 + kg8);
        #pragma unroll
        for (int m = 0; m < 4; ++m)
            #pragma unroll
            for (int n = 0; n < 4; ++n)
                acc[m][n] = __builtin_amdgcn_mfma_f32_16x16x32_bf16(a[m], b[n], acc[m][n], 0, 0, 0);
    }

    const int orow = (l >> 4) * 4;
    #pragma unroll
    for (int m = 0; m < 4; ++m) {
        #pragma unroll
        for (int i = 0; i < 4; ++i) {
            int r = r0 + m*16 + orow + i;
            if (r < PRED_OUT) {
                unsigned short* dst = S + (size_t)r*NT + tt0 + lr;
                #pragma unroll
                for (int n = 0; n < 4; ++n) dst[n*16] = f2bf(acc[m][n][i]);
            }
        }
    }
}

// Row-centric scatter+finalize: TWO rows per 512-thread block (each 256-thread
// half owns one row). Halves block-epoch count; 32KB LDS -> 4 blocks/CU (32 waves).
// Pre-barrier independent loads overlap the stage.
__global__ __launch_bounds__(512) void pred_scatter(const int2* __restrict__ PVU,
    const int* __restrict__ KN,
    const float* __restrict__ predw, const float* __restrict__ predb,
    const float* __restrict__ kg, const unsigned short* __restrict__ S,
    const float* __restrict__ ELT, float* __restrict__ rowp,
    int NT, int t0, int chunk) {
    __shared__ unsigned short srow[2][NLOCAS + NUSERS];   // 2 x 16 KB (bf16)
    __shared__ float red[8];
    const int tid  = threadIdx.x;
    const int half = tid >> 8;           // which row this thread serves
    const int ht   = tid & 255;          // thread id within half
    const int lane = tid & 63, wid = tid >> 6;
    const int r = blockIdx.x * 2 + half;
    const int mode = (r < DD) ? 0 : (r < DD + NLOCAS ? 1 : 2);
    const bool active = ht < (NT >> 3);  // 8 t per thread

    // ---- pre-barrier independent loads (overlap with stage) ----
    ushort8v sv = (ushort8v)0;
    int4 pv4[4];
    int4 kn0 = make_int4(0,0,0,0), kn1 = make_int4(0,0,0,0);
    float4 e0 = make_float4(0,0,0,0), e1 = make_float4(0,0,0,0);
    if (active) {
        sv = *(const ushort8v*)(S + (size_t)r*NT + ht*8);
        #pragma unroll
        for (int q = 0; q < 4; ++q)
            pv4[q] = *(const int4*)(PVU + t0 + ht*8 + q*2);
        if (mode == 0) {
            e0 = *(const float4*)(ELT + r*T_STEPS + t0 + ht*8);
            e1 = *(const float4*)(ELT + r*T_STEPS + t0 + ht*8 + 4);
        } else if (mode == 2) {
            kn0 = *(const int4*)(KN + t0 + ht*8);
            kn1 = *(const int4*)(KN + t0 + ht*8 + 4);
        }
    }

    // ---- stage this half's 32KB row as bf16 (16KB LDS) ----
    const float* base = predw + (size_t)r*PRED_IN + 320;
    #pragma unroll
    for (int i = 0; i < 8; ++i) {
        int idx = (ht + i*256) * 4;
        if (idx < NLOCAS + NUSERS) {
            float4 v = *(const float4*)(base + idx);
            ushort4v o;
            o.x = f2bf(v.x); o.y = f2bf(v.y); o.z = f2bf(v.z); o.w = f2bf(v.w);
            *(ushort4v*)(srow[half] + idx) = o;
        }
    }
    __syncthreads();

    const float bias = predb[r];
    const int kcol = r - DD - NLOCAS;
    float lsum = 0.f;
    if (active) {
        const float ee[8] = {e0.x, e0.y, e0.z, e0.w, e1.x, e1.y, e1.z, e1.w};
        const int kk[8] = {kn0.x, kn0.y, kn0.z, kn0.w, kn1.x, kn1.y, kn1.z, kn1.w};
        const int pvs[8] = {pv4[0].x, pv4[0].z, pv4[1].x, pv4[1].z,
                            pv4[2].x, pv4[2].z, pv4[3].x, pv4[3].z};
        const int uus[8] = {pv4[0].y, pv4[0].w, pv4[1].y, pv4[1].w,
                            pv4[2].y, pv4[2].w, pv4[3].y, pv4[3].w};
        const unsigned short* sr = srow[half];
        #pragma unroll
        for (int q = 0; q < 8; ++q) {
            const int pv = pvs[q], uu = uus[q];
            float v = bf2f(sv[q]) + bias + bf2f(sr[pv]) + bf2f(sr[NLOCAS + uu]);
            float tv;
            if (mode == 0)      tv = ee[q];
            else if (mode == 1) tv = (pv == r - DD) ? 1.f : 0.f;
            else                tv = kg[kk[q]*KK + kcol];
            float d = v - tv;
            lsum += d*d;
        }
    }
    #pragma unroll
    for (int o = 32; o > 0; o >>= 1) lsum += __shfl_xor(lsum, o, 64);
    if (lane == 0) red[wid] = lsum;
    __syncthreads();
    if (ht == 0)
        rowp[chunk*PRED_OUT + r] = red[half*4+0] + red[half*4+1]
                                 + red[half*4+2] + red[half*4+3];
}

__global__ __launch_bounds__(256) void final_reduce(const float* __restrict__ rowp,
                                                    const float* __restrict__ drift,
                                                    float* __restrict__ out, int nchunk) {
    int tid = threadIdx.x;
    float s = 0.f;
    for (int i = tid; i < nchunk*PRED_OUT; i += 256) s += rowp[i];
    s *= (1.0f / PRED_OUT);
    for (int i = tid; i < T_STEPS; i += 256) s += drift[i];
    #pragma unroll
    for (int o = 32; o > 0; o >>= 1) s += __shfl_xor(s, o, 64);
    __shared__ float red[4];
    if ((tid & 63) == 0) red[tid >> 6] = s;
    __syncthreads();
    if (tid == 0) out[OUT_EMB] = red[0] + red[1] + red[2] + red[3];
}

extern "C" void kernel_launch(void* const* d_in, const int* in_sizes, int n_in,
                              void* d_out, int out_size, void* d_ws, size_t ws_size,
                              hipStream_t stream) {
    const float* emb_in = (const float*)d_in[0];
    const int*   ev     = (const int*)  d_in[1];
    const float* du     = (const float*)d_in[2];
    const float* dl     = (const float*)d_in[3];
    const float* kg     = (const float*)d_in[4];
    const float* wihu   = (const float*)d_in[5];
    const float* whhu   = (const float*)d_in[6];
    const float* bihu   = (const float*)d_in[7];
    const float* bhhu   = (const float*)d_in[8];
    const float* wihl   = (const float*)d_in[9];
    const float* whhl   = (const float*)d_in[10];
    const float* bihl   = (const float*)d_in[11];
    const float* bhhl   = (const float*)d_in[12];
    const float* projw  = (const float*)d_in[13];
    const float* projb  = (const float*)d_in[14];
    const float* predw  = (const float*)d_in[15];
    const float* predb  = (const float*)d_in[16];

    float* out = (float*)d_out;
    float* ws  = (float*)d_ws;
    float* NEWU  = ws + WS_NEWU;
    float* NEWL  = ws + WS_NEWL;
    float* KU    = ws + WS_KU;
    float* KL    = ws + WS_KL;
    unsigned short* Zb = (unsigned short*)(ws + WS_ZB);
    unsigned short* Wb = (unsigned short*)(ws + WS_WB);
    float* ELT   = ws + WS_ELT;
    float* DRIFT = ws + WS_DRIFT;
    float* ROWP  = ws + WS_ROWP;
    int2*  PVU   = (int2*)(ws + WS_PVU);
    int*   KN    = (int*)(ws + WS_PVU) + 4096;
    unsigned short* S = (unsigned short*)(ws + WS_S);
    int*   ibase = (int*)(ws + WS_INT);

    long cap = ((long)ws_size - (long)WS_S*4) / 2;   // ushort slots for S
    int NT = 2048;
    while (NT > 128 && (long)PRED_OUT * NT > cap) NT >>= 1;
    int nchunk = T_STEPS / NT;

    prep_kernel<<<1024, 256, 0, stream>>>(ev, emb_in, du, dl, kg,
                                          wihu, bihu, bhhu, wihl, bihl, bhhl,
                                          predw, out, KU, KL, Wb, ibase);
    levels_kernel<<<1, 1024, 0, stream>>>(ibase);
    for (int lv = 0; lv < TAIL_LV; ++lv)
        chain_sweep<<<256, 512, 0, stream>>>(lv, ev, emb_in, wihu, whhu, whhl, wihl,
                                             KU, KL, NEWU, NEWL, DRIFT, ibase);
    chain_tail<<<1, 512, 0, stream>>>(ev, emb_in, wihu, whhu, whhl, wihl,
                                      KU, KL, NEWU, NEWL, DRIFT, ibase);
    build_z<<<1024, 256, 0, stream>>>(ev, emb_in, du, projw, projb, kg,
                                      NEWU, NEWL, Zb, ELT, PVU, KN, out, ibase);
    for (int c = 0; c < nchunk; ++c) {
        int t0 = c * NT;
        pred_dense_mfma<<<dim3(NT/128, 33), 256, 0, stream>>>(Wb, Zb, S, NT, t0);
        pred_scatter<<<PRED_OUT/2, 512, 0, stream>>>(PVU, KN, predw, predb, kg, S, ELT,
                                                     ROWP, NT, t0, c);
    }
    final_reduce<<<1, 256, 0, stream>>>(ROWP, DRIFT, out, nchunk);
}